// Round 1
// baseline (6899.579 us; speedup 1.0000x reference)
//
#include <hip/hip_runtime.h>
#include <hip/hip_bf16.h>

using bf16 = __hip_bfloat16;
typedef __attribute__((ext_vector_type(8))) short short8;   // 8 bf16 = 4 VGPRs (MFMA A/B frag)
typedef __attribute__((ext_vector_type(4))) float f32x4;    // MFMA C/D frag

#define MFMA16(A, B, C) __builtin_amdgcn_mfma_f32_16x16x32_bf16(A, B, C, 0, 0, 0)

constexpr int BM = 128, BN = 128, BK = 64;
constexpr int Mdim = 512;
constexpr int Ddim = 1024;
constexpr int Hdim = 2048;
constexpr size_t MN = (size_t)Mdim * Ddim;   // 512*1024 elements (y / k / A shape)

constexpr double Hs = 1.0 / 16.0;  // step size h
// CF[s-1][j]: coefficient of k_{j+1} (times h) in the combination produced after stage s.
// For s<6 it builds A_{s+1} = y + sum_j CF*k_j ; for s==6 it builds y_next (5th-order weights).
constexpr float CF[6][6] = {
    {float(Hs * 1 / 5.), 0.f, 0.f, 0.f, 0.f, 0.f},
    {float(Hs * 3 / 40.), float(Hs * 9 / 40.), 0.f, 0.f, 0.f, 0.f},
    {float(Hs * 44 / 45.), float(-Hs * 56 / 15.), float(Hs * 32 / 9.), 0.f, 0.f, 0.f},
    {float(Hs * 19372 / 6561.), float(-Hs * 25360 / 2187.), float(Hs * 64448 / 6561.),
     float(-Hs * 212 / 729.), 0.f, 0.f},
    {float(Hs * 9017 / 3168.), float(-Hs * 355 / 33.), float(Hs * 46732 / 5247.),
     float(Hs * 49 / 176.), float(-Hs * 5103 / 18656.), 0.f},
    {float(Hs * 35 / 384.), 0.f, float(Hs * 500 / 1113.), float(Hs * 125 / 192.),
     float(-Hs * 2187 / 6784.), float(Hs * 11 / 84.)},
};

__device__ __forceinline__ float tanh_fast(float x) {
  // tanh(x) = (e^{2x}-1)/(e^{2x}+1); clamp so exp never overflows (tanh(15)==1 in f32)
  float xc = fminf(fmaxf(x, -15.0f), 15.0f);
  float t = __expf(2.0f * xc);
  return (t - 1.0f) * __builtin_amdgcn_rcpf(t + 1.0f);
}

__device__ __forceinline__ void gload_lds16(const void* g, void* lds) {
  __builtin_amdgcn_global_load_lds((const __attribute__((address_space(1))) void*)g,
                                   (__attribute__((address_space(3))) void*)lds, 16, 0, 0);
}

// Stage one [128][64] bf16 tile (16 KB) : 4 iters x 256 threads x 16B, linear LDS layout.
__device__ __forceinline__ void stage_tile(const bf16* __restrict__ src, int ld,
                                           bf16* lds_base, int tid) {
#pragma unroll
  for (int it = 0; it < 4; ++it) {
    int chunk = it * 256 + tid;
    int r = chunk >> 3;
    int kc = (chunk & 7) << 3;
    gload_lds16(src + (size_t)r * ld + kc, lds_base + chunk * 8);
  }
}

// C = A(MxK,bf16 row-major) * Bt^T (Bt is [N][K] bf16 row-major) ; 128x128 tile, 4 waves.
// MODE 0: Hout = bf16(tanh(C + bias))            (GEMM1)
// MODE 1: k_S = C + bias ; store k_S (S<6) ; Anext = bf16(y + sum CF[S-1][j]*k_j)
//         and for S==6 also y = that combination (y_next).     (GEMM2, stage S)
template <int MODE, int STAGE>
__global__ __launch_bounds__(256) void fused_gemm(
    const bf16* __restrict__ A, const bf16* __restrict__ Bt, const float* __restrict__ bias,
    int K, int N, bf16* __restrict__ Hout, float* __restrict__ y, float* __restrict__ ks,
    bf16* __restrict__ Anext) {
  __shared__ bf16 sA[2][BM * BK];
  __shared__ bf16 sB[2][BN * BK];

  const int tid = threadIdx.x;
  const int lane = tid & 63;
  const int wid = tid >> 6;
  const int wr = wid >> 1, wc = wid & 1;  // 2x2 waves, each 64x64 output
  const int fr = lane & 15;               // A-row / B-col within fragment
  const int kg = lane >> 4;               // k-group (k = kg*8 .. +8)

  const int brow = blockIdx.y * BM;
  const int bcol = blockIdx.x * BN;
  const bf16* Ablk = A + (size_t)brow * K;
  const bf16* Bblk = Bt + (size_t)bcol * K;

  f32x4 acc[4][4] = {};

  const int nt = K / BK;
  stage_tile(Ablk, K, sA[0], tid);
  stage_tile(Bblk, K, sB[0], tid);
  asm volatile("s_waitcnt vmcnt(0)" ::: "memory");
  __syncthreads();

  int cur = 0;
  for (int t = 0; t < nt; ++t) {
    if (t + 1 < nt) {  // prefetch next K-tile into the other buffer (hides HBM/L2 latency)
      stage_tile(Ablk + (t + 1) * BK, K, sA[cur ^ 1], tid);
      stage_tile(Bblk + (t + 1) * BK, K, sB[cur ^ 1], tid);
    }
    const bf16* a0 = &sA[cur][(wr * 64 + fr) * BK + kg * 8];
    const bf16* b0 = &sB[cur][(wc * 64 + fr) * BK + kg * 8];
#pragma unroll
    for (int kk = 0; kk < 2; ++kk) {
      short8 af[4], bv[4];
#pragma unroll
      for (int m = 0; m < 4; ++m) af[m] = *(const short8*)(a0 + m * 16 * BK + kk * 32);
#pragma unroll
      for (int n = 0; n < 4; ++n) bv[n] = *(const short8*)(b0 + n * 16 * BK + kk * 32);
#pragma unroll
      for (int m = 0; m < 4; ++m)
#pragma unroll
        for (int n = 0; n < 4; ++n) acc[m][n] = MFMA16(af[m], bv[n], acc[m][n]);
    }
    asm volatile("s_waitcnt vmcnt(0)" ::: "memory");
    __syncthreads();
    cur ^= 1;
  }

  // Epilogue. C/D frag layout (m89-verified): col = lane&15, row = (lane>>4)*4 + e.
  const int r0 = brow + wr * 64 + kg * 4;
  const int c0 = bcol + wc * 64 + fr;
#pragma unroll
  for (int m = 0; m < 4; ++m) {
#pragma unroll
    for (int n = 0; n < 4; ++n) {
      const int c = c0 + n * 16;
      const float bvs = bias[c];
#pragma unroll
      for (int e = 0; e < 4; ++e) {
        const int r = r0 + m * 16 + e;
        const size_t idx = (size_t)r * N + c;
        if constexpr (MODE == 0) {
          Hout[idx] = __float2bfloat16(tanh_fast(acc[m][n][e] + bvs));
        } else {
          const float kv = acc[m][n][e] + bvs;
          if constexpr (STAGE < 6) ks[(size_t)(STAGE - 1) * MN + idx] = kv;
          float comb = y[idx] + CF[STAGE - 1][STAGE - 1] * kv;
          if constexpr (STAGE >= 2 && CF[STAGE - 1][0] != 0.f)
            comb += CF[STAGE - 1][0] * ks[0 * MN + idx];
          if constexpr (STAGE >= 3 && CF[STAGE - 1][1] != 0.f)
            comb += CF[STAGE - 1][1] * ks[1 * MN + idx];
          if constexpr (STAGE >= 4 && CF[STAGE - 1][2] != 0.f)
            comb += CF[STAGE - 1][2] * ks[2 * MN + idx];
          if constexpr (STAGE >= 5 && CF[STAGE - 1][3] != 0.f)
            comb += CF[STAGE - 1][3] * ks[3 * MN + idx];
          if constexpr (STAGE == 6 && CF[STAGE - 1][4] != 0.f)
            comb += CF[STAGE - 1][4] * ks[4 * MN + idx];
          if constexpr (STAGE == 6) y[idx] = comb;
          Anext[idx] = __float2bfloat16(comb);
        }
      }
    }
  }
}

// fp32 [R][C] -> bf16 [C][R] (weights: once per call)
__global__ void transpose_to_bf16(const float* __restrict__ in, bf16* __restrict__ out, int R,
                                  int C) {
  __shared__ float t[32][33];
  const int c0 = blockIdx.x * 32, r0 = blockIdx.y * 32;
#pragma unroll
  for (int i = threadIdx.y; i < 32; i += 8)
    t[i][threadIdx.x] = in[(size_t)(r0 + i) * C + c0 + threadIdx.x];
  __syncthreads();
#pragma unroll
  for (int i = threadIdx.y; i < 32; i += 8)
    out[(size_t)(c0 + i) * R + r0 + threadIdx.x] = __float2bfloat16(t[threadIdx.x][i]);
}

__global__ void init_y(const float* __restrict__ x, float* __restrict__ y,
                       bf16* __restrict__ A, int n) {
  int i = blockIdx.x * blockDim.x + threadIdx.x;
  if (i < n) {
    float v = x[i];
    y[i] = v;
    A[i] = __float2bfloat16(v);
  }
}

extern "C" void kernel_launch(void* const* d_in, const int* in_sizes, int n_in, void* d_out,
                              int out_size, void* d_ws, size_t ws_size, hipStream_t stream) {
  const float* x = (const float*)d_in[0];
  const float* W1 = (const float*)d_in[1];
  const float* b1 = (const float*)d_in[2];
  const float* W2 = (const float*)d_in[3];
  const float* b2 = (const float*)d_in[4];
  float* y = (float*)d_out;  // y lives in d_out; final step writes y_final here

  char* ws = (char*)d_ws;
  bf16* W1t = (bf16*)(ws + 0);                // [2048][1024] bf16, 4 MB
  bf16* W2t = (bf16*)(ws + (4ull << 20));     // [1024][2048] bf16, 4 MB
  bf16* Abuf = (bf16*)(ws + (8ull << 20));    // [512][1024] bf16 stage input, 1 MB
  bf16* Hbuf = (bf16*)(ws + (9ull << 20));    // [512][2048] bf16 hidden, 2 MB
  float* ks = (float*)(ws + (11ull << 20));   // 5 x [512][1024] f32 (k6 never stored), 10 MB

  transpose_to_bf16<<<dim3(Hdim / 32, Ddim / 32), dim3(32, 8), 0, stream>>>(W1, W1t, Ddim, Hdim);
  transpose_to_bf16<<<dim3(Ddim / 32, Hdim / 32), dim3(32, 8), 0, stream>>>(W2, W2t, Hdim, Ddim);
  init_y<<<(int)(MN / 256), 256, 0, stream>>>(x, y, Abuf, (int)MN);

#define LAUNCH_G1()                                                                   \
  fused_gemm<0, 0><<<dim3(Hdim / BN, Mdim / BM), 256, 0, stream>>>(                   \
      Abuf, W1t, b1, Ddim, Hdim, Hbuf, nullptr, nullptr, nullptr)
#define LAUNCH_G2(S)                                                                  \
  fused_gemm<1, S><<<dim3(Ddim / BN, Mdim / BM), 256, 0, stream>>>(                   \
      Hbuf, W2t, b2, Hdim, Ddim, nullptr, y, ks, Abuf)

  for (int step = 0; step < 16; ++step) {
    LAUNCH_G1(); LAUNCH_G2(1);
    LAUNCH_G1(); LAUNCH_G2(2);
    LAUNCH_G1(); LAUNCH_G2(3);
    LAUNCH_G1(); LAUNCH_G2(4);
    LAUNCH_G1(); LAUNCH_G2(5);
    LAUNCH_G1(); LAUNCH_G2(6);
  }
#undef LAUNCH_G1
#undef LAUNCH_G2
}

// Round 2
// 2599.076 us; speedup vs baseline: 2.6546x; 2.6546x over previous
//
#include <hip/hip_runtime.h>
#include <hip/hip_bf16.h>

using bf16 = __hip_bfloat16;
typedef __attribute__((ext_vector_type(8))) short short8;   // 8 bf16 = 4 VGPRs (MFMA A/B frag)
typedef __attribute__((ext_vector_type(4))) float f32x4;    // MFMA C/D frag

#define MFMA16(A, B, C) __builtin_amdgcn_mfma_f32_16x16x32_bf16(A, B, C, 0, 0, 0)

constexpr int Mdim = 512;
constexpr int Ddim = 1024;
constexpr int Hdim = 2048;
constexpr size_t MN = (size_t)Mdim * Ddim;   // 512*1024 elements (y / k / A shape)

constexpr double Hs = 1.0 / 16.0;  // step size h
// CF[s-1][j]: coefficient of k_{j+1} (times h) in the combination produced after stage s.
constexpr float CF[6][6] = {
    {float(Hs * 1 / 5.), 0.f, 0.f, 0.f, 0.f, 0.f},
    {float(Hs * 3 / 40.), float(Hs * 9 / 40.), 0.f, 0.f, 0.f, 0.f},
    {float(Hs * 44 / 45.), float(-Hs * 56 / 15.), float(Hs * 32 / 9.), 0.f, 0.f, 0.f},
    {float(Hs * 19372 / 6561.), float(-Hs * 25360 / 2187.), float(Hs * 64448 / 6561.),
     float(-Hs * 212 / 729.), 0.f, 0.f},
    {float(Hs * 9017 / 3168.), float(-Hs * 355 / 33.), float(Hs * 46732 / 5247.),
     float(Hs * 49 / 176.), float(-Hs * 5103 / 18656.), 0.f},
    {float(Hs * 35 / 384.), 0.f, float(Hs * 500 / 1113.), float(Hs * 125 / 192.),
     float(-Hs * 2187 / 6784.), float(Hs * 11 / 84.)},
};

__device__ __forceinline__ float tanh_fast(float x) {
  float xc = fminf(fmaxf(x, -15.0f), 15.0f);
  float t = __expf(2.0f * xc);
  return (t - 1.0f) * __builtin_amdgcn_rcpf(t + 1.0f);
}

__device__ __forceinline__ void gload_lds16(const void* g, void* lds) {
  __builtin_amdgcn_global_load_lds((const __attribute__((address_space(1))) void*)g,
                                   (__attribute__((address_space(3))) void*)lds, 16, 0, 0);
}

// Stage a [ROWS][BK] bf16 tile. LDS destination is LINEAR in chunk order (global_load_lds
// writes wave-uniform-base + lane*16B); the XOR swizzle is applied to the GLOBAL SOURCE
// chunk index (involution c ^= r&7 on 16B chunks), per both-sides-or-neither rule.
template <int ROWS, int BK>
__device__ __forceinline__ void stage_tile(const bf16* __restrict__ src, int ld,
                                           bf16* lds_base, int tid) {
  constexpr int CH = BK / 8;          // 16B chunks per row
  constexpr int NCH = ROWS * CH;
#pragma unroll
  for (int q0 = 0; q0 < NCH; q0 += 256) {
    const int q = q0 + tid;           // linear LDS chunk slot (lane-contiguous)
    const int r = q / CH;
    const int cs = q % CH;
    const int cg = cs ^ (r & 7);      // source chunk for this slot (involution)
    gload_lds16(src + (size_t)r * ld + cg * 8, lds_base + q * 8);
  }
}

// Read fragment chunk (row, c) through the same swizzle.
template <int BK>
__device__ __forceinline__ short8 lds_frag(const bf16* s, int row, int c) {
  return *(const short8*)(s + row * BK + ((c ^ (row & 7)) << 3));
}

// C = A(MxK bf16 rm) * Bt^T (Bt [N][K] bf16 rm); BMxBN tile, 4 waves in 2x2.
// MODE 0: Hout = bf16(tanh(C + bias))                              (GEMM1)
// MODE 1: k_S = C + bias; store bf16 k_S (S<6); Anext = bf16(y + sum CF*k_j);
//         S==6 additionally writes y (f32, 5th-order update).      (GEMM2 stage S)
template <int MODE, int STAGE, int BM, int BN, int BK>
__global__ __launch_bounds__(256) void fused_gemm(
    const bf16* __restrict__ A, const bf16* __restrict__ Bt, const float* __restrict__ bias,
    int K, int N, bf16* __restrict__ Hout, float* __restrict__ y, bf16* __restrict__ ks,
    bf16* __restrict__ Anext) {
  constexpr int WTM = BM / 2, WTN = BN / 2;   // per-wave tile
  constexpr int MR = WTM / 16, NR = WTN / 16; // frags per wave
  constexpr int KK = BK / 32;                 // MFMA k-steps per K-tile

  __shared__ bf16 sA[2][BM * BK];
  __shared__ bf16 sB[2][BN * BK];

  const int tid = threadIdx.x;
  const int lane = tid & 63;
  const int wid = tid >> 6;
  const int wr = wid >> 1, wc = wid & 1;
  const int fr = lane & 15;   // A-row / B-col within fragment
  const int kg = lane >> 4;   // k-subchunk group

  const int brow = blockIdx.y * BM;
  const int bcol = blockIdx.x * BN;
  const bf16* Ablk = A + (size_t)brow * K;
  const bf16* Bblk = Bt + (size_t)bcol * K;

  f32x4 acc[MR][NR] = {};

  const int nt = K / BK;
  stage_tile<BM, BK>(Ablk, K, sA[0], tid);
  stage_tile<BN, BK>(Bblk, K, sB[0], tid);
  asm volatile("s_waitcnt vmcnt(0)" ::: "memory");
  __syncthreads();

  int cur = 0;
  for (int t = 0; t < nt; ++t) {
    if (t + 1 < nt) {
      stage_tile<BM, BK>(Ablk + (t + 1) * BK, K, sA[cur ^ 1], tid);
      stage_tile<BN, BK>(Bblk + (t + 1) * BK, K, sB[cur ^ 1], tid);
    }
    const bf16* sa = sA[cur];
    const bf16* sb = sB[cur];
#pragma unroll
    for (int kk = 0; kk < KK; ++kk) {
      const int c = kk * 4 + kg;
      short8 af[MR], bv[NR];
#pragma unroll
      for (int m = 0; m < MR; ++m) af[m] = lds_frag<BK>(sa, wr * WTM + m * 16 + fr, c);
#pragma unroll
      for (int n = 0; n < NR; ++n) bv[n] = lds_frag<BK>(sb, wc * WTN + n * 16 + fr, c);
#pragma unroll
      for (int m = 0; m < MR; ++m)
#pragma unroll
        for (int n = 0; n < NR; ++n) acc[m][n] = MFMA16(af[m], bv[n], acc[m][n]);
    }
    asm volatile("s_waitcnt vmcnt(0)" ::: "memory");
    __syncthreads();
    cur ^= 1;
  }

  // Epilogue. C/D frag layout (m89-verified): col = lane&15, row = (lane>>4)*4 + e.
  const int r0 = brow + wr * WTM + kg * 4;
  const int c0 = bcol + wc * WTN + fr;
#pragma unroll
  for (int m = 0; m < MR; ++m) {
#pragma unroll
    for (int n = 0; n < NR; ++n) {
      const int c = c0 + n * 16;
      const float bvs = bias[c];
#pragma unroll
      for (int e = 0; e < 4; ++e) {
        const int r = r0 + m * 16 + e;
        const size_t idx = (size_t)r * N + c;
        if constexpr (MODE == 0) {
          Hout[idx] = __float2bfloat16(tanh_fast(acc[m][n][e] + bvs));
        } else {
          const float kv = acc[m][n][e] + bvs;
          if constexpr (STAGE < 6) ks[(size_t)(STAGE - 1) * MN + idx] = __float2bfloat16(kv);
          float comb = y[idx] + CF[STAGE - 1][STAGE - 1] * kv;
          if constexpr (STAGE >= 2 && CF[STAGE - 1][0] != 0.f)
            comb += CF[STAGE - 1][0] * __bfloat162float(ks[0 * MN + idx]);
          if constexpr (STAGE >= 3 && CF[STAGE - 1][1] != 0.f)
            comb += CF[STAGE - 1][1] * __bfloat162float(ks[1 * MN + idx]);
          if constexpr (STAGE >= 4 && CF[STAGE - 1][2] != 0.f)
            comb += CF[STAGE - 1][2] * __bfloat162float(ks[2 * MN + idx]);
          if constexpr (STAGE >= 5 && CF[STAGE - 1][3] != 0.f)
            comb += CF[STAGE - 1][3] * __bfloat162float(ks[3 * MN + idx]);
          if constexpr (STAGE == 6 && CF[STAGE - 1][4] != 0.f)
            comb += CF[STAGE - 1][4] * __bfloat162float(ks[4 * MN + idx]);
          if constexpr (STAGE == 6) y[idx] = comb;
          Anext[idx] = __float2bfloat16(comb);
        }
      }
    }
  }
}

// fp32 [R][C] -> bf16 [C][R] (weights: once per call)
__global__ void transpose_to_bf16(const float* __restrict__ in, bf16* __restrict__ out, int R,
                                  int C) {
  __shared__ float t[32][33];
  const int c0 = blockIdx.x * 32, r0 = blockIdx.y * 32;
#pragma unroll
  for (int i = threadIdx.y; i < 32; i += 8)
    t[i][threadIdx.x] = in[(size_t)(r0 + i) * C + c0 + threadIdx.x];
  __syncthreads();
#pragma unroll
  for (int i = threadIdx.y; i < 32; i += 8)
    out[(size_t)(c0 + i) * R + r0 + threadIdx.x] = __float2bfloat16(t[threadIdx.x][i]);
}

__global__ void init_y(const float* __restrict__ x, float* __restrict__ y,
                       bf16* __restrict__ A, int n) {
  int i = blockIdx.x * blockDim.x + threadIdx.x;
  if (i < n) {
    float v = x[i];
    y[i] = v;
    A[i] = __float2bfloat16(v);
  }
}

struct Ptrs {
  const float *b1, *b2;
  bf16 *W1t, *W2t, *Abuf, *Hbuf, *ks;
  float* y;
};

static inline void launch_g1(const Ptrs& p, hipStream_t stream) {
  fused_gemm<0, 0, 64, 64, 128><<<dim3(Hdim / 64, Mdim / 64), 256, 0, stream>>>(
      p.Abuf, p.W1t, p.b1, Ddim, Hdim, p.Hbuf, nullptr, nullptr, nullptr);
}
template <int S>
static inline void launch_g2(const Ptrs& p, hipStream_t stream) {
  fused_gemm<1, S, 32, 64, 128><<<dim3(Ddim / 64, Mdim / 32), 256, 0, stream>>>(
      p.Hbuf, p.W2t, p.b2, Hdim, Ddim, nullptr, p.y, p.ks, p.Abuf);
}

extern "C" void kernel_launch(void* const* d_in, const int* in_sizes, int n_in, void* d_out,
                              int out_size, void* d_ws, size_t ws_size, hipStream_t stream) {
  const float* x = (const float*)d_in[0];
  const float* W1 = (const float*)d_in[1];
  const float* b1 = (const float*)d_in[2];
  const float* W2 = (const float*)d_in[3];
  const float* b2 = (const float*)d_in[4];
  float* y = (float*)d_out;

  char* ws = (char*)d_ws;
  Ptrs p;
  p.b1 = b1;
  p.b2 = b2;
  p.W1t = (bf16*)(ws + 0);               // [2048][1024] bf16, 4 MB
  p.W2t = (bf16*)(ws + (4ull << 20));    // [1024][2048] bf16, 4 MB
  p.Abuf = (bf16*)(ws + (8ull << 20));   // [512][1024] bf16 stage input, 1 MB
  p.Hbuf = (bf16*)(ws + (9ull << 20));   // [512][2048] bf16 hidden, 2 MB
  p.ks = (bf16*)(ws + (11ull << 20));    // 5 x [512][1024] bf16, 5 MB
  p.y = y;

  transpose_to_bf16<<<dim3(Hdim / 32, Ddim / 32), dim3(32, 8), 0, stream>>>(W1, p.W1t, Ddim, Hdim);
  transpose_to_bf16<<<dim3(Ddim / 32, Hdim / 32), dim3(32, 8), 0, stream>>>(W2, p.W2t, Hdim, Ddim);
  init_y<<<(int)(MN / 256), 256, 0, stream>>>(x, y, p.Abuf, (int)MN);

  for (int step = 0; step < 16; ++step) {
    launch_g1(p, stream); launch_g2<1>(p, stream);
    launch_g1(p, stream); launch_g2<2>(p, stream);
    launch_g1(p, stream); launch_g2<3>(p, stream);
    launch_g1(p, stream); launch_g2<4>(p, stream);
    launch_g1(p, stream); launch_g2<5>(p, stream);
    launch_g1(p, stream); launch_g2<6>(p, stream);
  }
}